// Round 11
// baseline (560.112 us; speedup 1.0000x reference)
//
#include <hip/hip_runtime.h>

#define NN 100000
#define NE 1600000
#define D 128
#define NG 1024
#define SCAN_CHUNK 2048
#define NB ((NN + SCAN_CHUNK - 1) / SCAN_CHUNK)   // 49
#define GEMM_BLKS ((NN + 127) / 128)              // 782
#define HIST_BLKS ((NE + 255) / 256)              // 6250
#define BOUNDS_BLKS 5                             // 5*256 >= NG+1

// ---------------- GEMM body: out[r][c] = sum_k act(in[r][k]) * W[k][c] ----------------
// 128x128 tile, K in 8 double-buffered panels of 16. 256 thr, per-thread 8x8.
// W panel stored float4-slot XOR-swizzled (f ^= (f>>3)&1) so column reads are
// 2-way (free) instead of 4-way bank conflicts. Single barrier per panel.
__device__ __forceinline__ void gemm_body(const float* __restrict__ in,
                                          const float* __restrict__ W,
                                          const float* __restrict__ bias_in,
                                          int relu_in,
                                          float* __restrict__ out,
                                          int blk) {
    __shared__ float xs[2][16][132];   // [buf][k][row] transposed x panel
    __shared__ float ws[2][16][128];   // [buf][k][col] swizzled float4 slots

    int tid  = threadIdx.x;
    int row0 = blk * 128;

    int srow = tid >> 2;               // x staging rows srow, srow+64
    int skq  = (tid & 3) * 4;          // k-quad
    int wkr  = tid >> 5;               // W staging k-rows wkr, wkr+8
    int fw   = tid & 31;               // logical float4 slot (cols fw*4..+3)
    int fws  = fw ^ ((fw >> 3) & 1);   // swizzled slot
    int tx = tid & 15, ty = tid >> 4;
    int r0 = ty * 8, c0 = tx * 8;
    int f0 = (2 * tx) ^ ((tx >> 2) & 1);   // swizzled slot of logical 2tx
    int f1 = f0 ^ 1;                       // swizzled slot of logical 2tx+1

    float4 lx0, lx1, lw0, lw1;

    auto LOAD = [&](int kp) {
        int k0 = kp * 16;
        int rg0 = row0 + srow;      if (rg0 >= NN) rg0 = NN - 1;
        int rg1 = row0 + srow + 64; if (rg1 >= NN) rg1 = NN - 1;
        lx0 = *(const float4*)(in + (size_t)rg0 * D + k0 + skq);
        lx1 = *(const float4*)(in + (size_t)rg1 * D + k0 + skq);
        lw0 = *(const float4*)(W + (size_t)(k0 + wkr) * D + fw * 4);
        lw1 = *(const float4*)(W + (size_t)(k0 + 8 + wkr) * D + fw * 4);
        if (relu_in) {
            float4 bb = *(const float4*)(bias_in + k0 + skq);
            lx0.x = fmaxf(lx0.x + bb.x, 0.f); lx0.y = fmaxf(lx0.y + bb.y, 0.f);
            lx0.z = fmaxf(lx0.z + bb.z, 0.f); lx0.w = fmaxf(lx0.w + bb.w, 0.f);
            lx1.x = fmaxf(lx1.x + bb.x, 0.f); lx1.y = fmaxf(lx1.y + bb.y, 0.f);
            lx1.z = fmaxf(lx1.z + bb.z, 0.f); lx1.w = fmaxf(lx1.w + bb.w, 0.f);
        }
    };
    auto WRITE = [&](int buf) {
        xs[buf][skq + 0][srow]      = lx0.x;
        xs[buf][skq + 1][srow]      = lx0.y;
        xs[buf][skq + 2][srow]      = lx0.z;
        xs[buf][skq + 3][srow]      = lx0.w;
        xs[buf][skq + 0][srow + 64] = lx1.x;
        xs[buf][skq + 1][srow + 64] = lx1.y;
        xs[buf][skq + 2][srow + 64] = lx1.z;
        xs[buf][skq + 3][srow + 64] = lx1.w;
        ((float4*)ws[buf][wkr])[fws]     = lw0;
        ((float4*)ws[buf][wkr + 8])[fws] = lw1;
    };

    float acc[8][8] = {};

    LOAD(0);
    WRITE(0);
    __syncthreads();

    for (int kp = 0; kp < 8; ++kp) {
        int cur = kp & 1;
        if (kp < 7) LOAD(kp + 1);      // global loads in flight over compute
#pragma unroll
        for (int kk = 0; kk < 16; ++kk) {
            float4 xa = *(const float4*)&xs[cur][kk][r0];
            float4 xb = *(const float4*)&xs[cur][kk][r0 + 4];
            float4 wa = ((const float4*)ws[cur][kk])[f0];
            float4 wb = ((const float4*)ws[cur][kk])[f1];
            float xv[8] = {xa.x, xa.y, xa.z, xa.w, xb.x, xb.y, xb.z, xb.w};
            float wv[8] = {wa.x, wa.y, wa.z, wa.w, wb.x, wb.y, wb.z, wb.w};
#pragma unroll
            for (int i = 0; i < 8; ++i)
#pragma unroll
                for (int j = 0; j < 8; ++j)
                    acc[i][j] += xv[i] * wv[j];
        }
        if (kp < 7) {
            WRITE(cur ^ 1);            // safe: cur^1 readers passed last barrier
            __syncthreads();
        }
    }

#pragma unroll
    for (int i = 0; i < 8; ++i) {
        int rg = row0 + r0 + i;
        if (rg < NN) {
            *(float4*)(out + (size_t)rg * D + c0) =
                make_float4(acc[i][0], acc[i][1], acc[i][2], acc[i][3]);
            *(float4*)(out + (size_t)rg * D + c0 + 4) =
                make_float4(acc[i][4], acc[i][5], acc[i][6], acc[i][7]);
        }
    }
}

// ---------------- hist (standalone, first) ----------------
__global__ __launch_bounds__(256) void k_hist(const int* __restrict__ dst,
                                              int* __restrict__ deg) {
    int e = blockIdx.x * 256 + threadIdx.x;
    if (e < NE) atomicAdd(&deg[dst[e]], 1);
}

// ---------------- K2: scanA (+dinv fused) || bounds ----------------
__global__ __launch_bounds__(256) void k_scanA(const int* __restrict__ deg,
                                               float* __restrict__ dinv,
                                               int* __restrict__ row_ptr,
                                               int* __restrict__ bsum,
                                               const int* __restrict__ batch,
                                               int* __restrict__ gstart) {
    int b = blockIdx.x, tid = threadIdx.x;
    if (b >= NB) {
        int g = (b - NB) * 256 + tid;
        if (g > NG) return;
        if (g == NG) { gstart[NG] = NN; return; }
        int lo = 0, hi = NN;               // first v with batch[v] >= g
        while (lo < hi) {
            int mid = (lo + hi) >> 1;
            if (batch[mid] < g) lo = mid + 1; else hi = mid;
        }
        gstart[g] = lo;
        return;
    }
    __shared__ int sh[256];
    int base = b * SCAN_CHUNK + tid * 8;
    int loc[8];
    int s = 0;
#pragma unroll
    for (int j = 0; j < 8; ++j) {
        int i = base + j;
        int d = (i < NN) ? deg[i] : 0;
        if (i < NN) dinv[i] = rsqrtf((float)(d + 1));   // +1 self-loop
        loc[j] = s;
        s += d;
    }
    sh[tid] = s;
    __syncthreads();
    for (int off = 1; off < 256; off <<= 1) {
        int v = (tid >= off) ? sh[tid - off] : 0;
        __syncthreads();
        sh[tid] += v;
        __syncthreads();
    }
    int excl = (tid == 0) ? 0 : sh[tid - 1];
#pragma unroll
    for (int j = 0; j < 8; ++j) {
        int i = base + j;
        if (i < NN) row_ptr[i] = excl + loc[j];
    }
    if (tid == 255) bsum[b] = sh[255];
}

// ---------------- K3: scanC with inline block-sum prefix ----------------
__global__ __launch_bounds__(256) void k_scanC(int* __restrict__ row_ptr,
                                               const int* __restrict__ bsum,
                                               int* __restrict__ fill) {
    __shared__ int sb[64];
    int tid = threadIdx.x;
    if (tid < NB) sb[tid] = bsum[tid];
    __syncthreads();
    int chunk = (blockIdx.x * 256) / SCAN_CHUNK;
    int pre = 0;
    for (int b = 0; b < chunk; ++b) pre += sb[b];   // uniform LDS broadcast
    int i = blockIdx.x * 256 + tid;
    if (i < NN) {
        int r = row_ptr[i] + pre;
        row_ptr[i] = r;
        fill[i] = r;
    }
    if (i == 0) row_ptr[NN] = NE;
}

// ---------------- K4: gemm1 (blocks 0..GEMM_BLKS) || CSR fill (rest) ----------------
__global__ __launch_bounds__(256) void k_gemm1_fill(const float* __restrict__ x,
                                                    const float* __restrict__ W1,
                                                    float* __restrict__ bufA,
                                                    const int* __restrict__ src,
                                                    const int* __restrict__ dst,
                                                    const float* __restrict__ dinv,
                                                    int* __restrict__ fillc,
                                                    int2* __restrict__ csr) {
    int b = blockIdx.x;
    if (b < GEMM_BLKS) {
        gemm_body(x, W1, nullptr, 0, bufA, b);
    } else {
        int e = (b - GEMM_BLKS) * 256 + threadIdx.x;
        if (e < NE) {
            int s = src[e], d = dst[e];
            float nrm = dinv[s] * dinv[d];
            int pos = atomicAdd(&fillc[d], 1);
            csr[pos] = make_int2(s, __float_as_int(nrm));
        }
    }
}

// ---------------- layer-2 GEMM ----------------
__global__ __launch_bounds__(256) void k_gemm(const float* __restrict__ in,
                                              const float* __restrict__ W,
                                              const float* __restrict__ bias_in,
                                              float* __restrict__ out) {
    gemm_body(in, W, bias_in, 1, out, blockIdx.x);
}

// ---------------- gather: agg[v] = h[v]*dinv[v]^2 + sum_in h[s]*norm ----------------
__global__ __launch_bounds__(256) void k_gather(const float* __restrict__ h,
                                                const int* __restrict__ row_ptr,
                                                const int2* __restrict__ csr,
                                                const float* __restrict__ dinv,
                                                float* __restrict__ agg) {
    int t = blockIdx.x * 256 + threadIdx.x;   // NN*32 threads
    int v = t >> 5;
    if (v >= NN) return;
    int c = (t & 31) * 4;

    float di = dinv[v];
    float sl = di * di;
    float4 acc = *(const float4*)(h + (size_t)v * D + c);
    acc.x *= sl; acc.y *= sl; acc.z *= sl; acc.w *= sl;

    int p   = row_ptr[v];
    int end = row_ptr[v + 1];
    for (; p + 3 < end; p += 4) {
        int2 e0 = csr[p], e1 = csr[p + 1], e2 = csr[p + 2], e3 = csr[p + 3];
        float n0 = __int_as_float(e0.y);
        float n1 = __int_as_float(e1.y);
        float n2 = __int_as_float(e2.y);
        float n3 = __int_as_float(e3.y);
        float4 h0 = *(const float4*)(h + (size_t)e0.x * D + c);
        float4 h1 = *(const float4*)(h + (size_t)e1.x * D + c);
        float4 h2 = *(const float4*)(h + (size_t)e2.x * D + c);
        float4 h3 = *(const float4*)(h + (size_t)e3.x * D + c);
        acc.x += h0.x * n0; acc.y += h0.y * n0; acc.z += h0.z * n0; acc.w += h0.w * n0;
        acc.x += h1.x * n1; acc.y += h1.y * n1; acc.z += h1.z * n1; acc.w += h1.w * n1;
        acc.x += h2.x * n2; acc.y += h2.y * n2; acc.z += h2.z * n2; acc.w += h2.w * n2;
        acc.x += h3.x * n3; acc.y += h3.y * n3; acc.z += h3.z * n3; acc.w += h3.w * n3;
    }
    for (; p < end; ++p) {
        int2 e0 = csr[p];
        float n0 = __int_as_float(e0.y);
        float4 h0 = *(const float4*)(h + (size_t)e0.x * D + c);
        acc.x += h0.x * n0; acc.y += h0.y * n0; acc.z += h0.z * n0; acc.w += h0.w * n0;
    }
    *(float4*)(agg + (size_t)v * D + c) = acc;
}

// ---------------- fused pool + classifier (2 graphs per 256-thread block) ----------------
__global__ __launch_bounds__(256) void k_poolcls(const float* __restrict__ agg,
                                                 const float* __restrict__ b2,
                                                 const int* __restrict__ gstart,
                                                 const float* __restrict__ Wc,
                                                 const float* __restrict__ bc,
                                                 float* __restrict__ out) {
    int half = threadIdx.x >> 7;        // 0 or 1
    int c    = threadIdx.x & 127;
    int g    = blockIdx.x * 2 + half;
    int v0 = gstart[g], v1 = gstart[g + 1];
    float bb = b2[c];
    float acc = 0.f;
    int v = v0;
    for (; v + 7 < v1; v += 8) {            // 8-deep for latency
        float x0 = agg[(size_t)(v + 0) * D + c];
        float x1 = agg[(size_t)(v + 1) * D + c];
        float x2 = agg[(size_t)(v + 2) * D + c];
        float x3 = agg[(size_t)(v + 3) * D + c];
        float x4 = agg[(size_t)(v + 4) * D + c];
        float x5 = agg[(size_t)(v + 5) * D + c];
        float x6 = agg[(size_t)(v + 6) * D + c];
        float x7 = agg[(size_t)(v + 7) * D + c];
        acc += fmaxf(x0 + bb, 0.f) + fmaxf(x1 + bb, 0.f)
             + fmaxf(x2 + bb, 0.f) + fmaxf(x3 + bb, 0.f)
             + fmaxf(x4 + bb, 0.f) + fmaxf(x5 + bb, 0.f)
             + fmaxf(x6 + bb, 0.f) + fmaxf(x7 + bb, 0.f);
    }
    for (; v < v1; ++v)
        acc += fmaxf(agg[(size_t)v * D + c] + bb, 0.f);

    float inv = 1.0f / fmaxf((float)(v1 - v0), 1.0f);
    float pv = acc * inv;

    __shared__ float red[2][2][128];
    red[half][0][c] = pv * Wc[c * 2 + 0];
    red[half][1][c] = pv * Wc[c * 2 + 1];
    __syncthreads();
    if (c < 64) {
        float s = red[half][0][c] + red[half][0][c + 64];
        for (int off = 32; off; off >>= 1) s += __shfl_down(s, off);
        if (c == 0) out[g * 2 + 0] = s + bc[0];
    } else {
        int l = c - 64;
        float s = red[half][1][l] + red[half][1][l + 64];
        for (int off = 32; off; off >>= 1) s += __shfl_down(s, off);
        if (l == 0) out[g * 2 + 1] = s + bc[1];
    }
}

extern "C" void kernel_launch(void* const* d_in, const int* in_sizes, int n_in,
                              void* d_out, int out_size, void* d_ws, size_t ws_size,
                              hipStream_t stream) {
    const float* x     = (const float*)d_in[0];
    const int*   ei    = (const int*)d_in[1];
    const int*   batch = (const int*)d_in[2];
    const float* W1    = (const float*)d_in[3];
    const float* b1    = (const float*)d_in[4];
    const float* W2    = (const float*)d_in[5];
    const float* b2    = (const float*)d_in[6];
    const float* Wc    = (const float*)d_in[7];
    const float* bc    = (const float*)d_in[8];
    float* out = (float*)d_out;

    const int* src = ei;            // edge_index[0]
    const int* dst = ei + NE;       // edge_index[1]

    char* p = (char*)d_ws;
    int*   deg_i   = (int*)p;    p += 100352 * 4;
    float* dinv    = (float*)p;  p += 100352 * 4;
    int*   row_ptr = (int*)p;    p += 100352 * 4;   // NN+1 fits
    int*   fillc   = (int*)p;    p += 100352 * 4;
    int*   bsum    = (int*)p;    p += 256 * 4;
    int*   gstart  = (int*)p;    p += 1056 * 4;     // NG+1
    int2*  csr     = (int2*)p;   p += (size_t)NE * 8;
    float* bufA    = (float*)p;  p += (size_t)NN * D * 4;
    float* bufB    = (float*)p;  p += (size_t)NN * D * 4;

    hipMemsetAsync(deg_i, 0, 100352 * 4, stream);

    // CSR build: hist first; fill hidden under layer-1 GEMM below
    k_hist <<<HIST_BLKS, 256, 0, stream>>>(dst, deg_i);
    k_scanA<<<NB + BOUNDS_BLKS, 256, 0, stream>>>(deg_i, dinv, row_ptr, bsum, batch, gstart);
    k_scanC<<<(NN + 255) / 256, 256, 0, stream>>>(row_ptr, bsum, fillc);

    // K4: layer-1 GEMM || CSR fill
    k_gemm1_fill<<<GEMM_BLKS + HIST_BLKS, 256, 0, stream>>>(x, W1, bufA, src, dst,
                                                            dinv, fillc, csr);
    // layer 1 gather
    k_gather<<<NN * 32 / 256, 256, 0, stream>>>(bufA, row_ptr, csr, dinv, bufB);

    // layer 2 (bias1+relu fused into gemm load)
    k_gemm<<<GEMM_BLKS, 256, 0, stream>>>(bufB, W2, b1, bufA);
    k_gather<<<NN * 32 / 256, 256, 0, stream>>>(bufA, row_ptr, csr, dinv, bufB);

    // fused pooling (bias2+relu) + classifier, 2 graphs/block
    k_poolcls<<<NG / 2, 256, 0, stream>>>(bufB, b2, gstart, Wc, bc, out);
}

// Round 12
// 548.621 us; speedup vs baseline: 1.0209x; 1.0209x over previous
//
#include <hip/hip_runtime.h>

#define NN 100000
#define NE 1600000
#define D 128
#define NG 1024
#define SCAN_CHUNK 2048
#define NB ((NN + SCAN_CHUNK - 1) / SCAN_CHUNK)   // 49
#define GEMM_BLKS ((NN + 63) / 64)                // 1563
#define HIST_BLKS ((NE + 255) / 256)              // 6250
#define BOUNDS_BLKS 5                             // 5*256 >= NG+1

// ---------------- GEMM body: out[r][c] = sum_k act(in[r][k]) * W[k][c] ----------------
// 64x128 tile, K in 8 double-buffered panels of 16. 256 thr, per-thread 4x8
// (VGPR ~84 -> 4+ blocks/CU). Single barrier per panel.
__device__ __forceinline__ void gemm_body(const float* __restrict__ in,
                                          const float* __restrict__ W,
                                          const float* __restrict__ bias_in,
                                          int relu_in,
                                          float* __restrict__ out,
                                          int blk) {
    __shared__ float xs[2][16][68];    // [buf][k][row] transposed panel (2-way max)
    __shared__ float ws[2][16][128];   // [buf][k][col] lane-sequential float4s

    int tid  = threadIdx.x;
    int row0 = blk * 64;

    int srow = tid >> 2;               // x staging row 0..63
    int skq  = (tid & 3) * 4;          // k-quad
    int wkr  = tid >> 5;               // W staging k-row
    int wcq  = (tid & 31) * 4;         // W col quad
    int tx = tid & 15, ty = tid >> 4;
    int r0 = ty * 4, c0 = tx * 4;      // cols c0 and c0+64

    float4 lx, lw0, lw1;

    auto LOAD = [&](int kp) {
        int k0 = kp * 16;
        int rg = row0 + srow; if (rg >= NN) rg = NN - 1;
        lx  = *(const float4*)(in + (size_t)rg * D + k0 + skq);
        lw0 = *(const float4*)(W + (size_t)(k0 + wkr) * D + wcq);
        lw1 = *(const float4*)(W + (size_t)(k0 + 8 + wkr) * D + wcq);
        if (relu_in) {
            float4 bb = *(const float4*)(bias_in + k0 + skq);
            lx.x = fmaxf(lx.x + bb.x, 0.f);
            lx.y = fmaxf(lx.y + bb.y, 0.f);
            lx.z = fmaxf(lx.z + bb.z, 0.f);
            lx.w = fmaxf(lx.w + bb.w, 0.f);
        }
    };
    auto WRITE = [&](int buf) {
        xs[buf][skq + 0][srow] = lx.x;
        xs[buf][skq + 1][srow] = lx.y;
        xs[buf][skq + 2][srow] = lx.z;
        xs[buf][skq + 3][srow] = lx.w;
        *(float4*)&ws[buf][wkr][wcq]     = lw0;
        *(float4*)&ws[buf][wkr + 8][wcq] = lw1;
    };

    float acc[4][8] = {};

    LOAD(0);
    WRITE(0);
    __syncthreads();

    for (int kp = 0; kp < 8; ++kp) {
        int cur = kp & 1;
        if (kp < 7) LOAD(kp + 1);      // global loads in flight over compute
#pragma unroll
        for (int kk = 0; kk < 16; ++kk) {
            float4 xa = *(const float4*)&xs[cur][kk][r0];
            float4 wa = *(const float4*)&ws[cur][kk][c0];
            float4 wb = *(const float4*)&ws[cur][kk][c0 + 64];
            float xv[4] = {xa.x, xa.y, xa.z, xa.w};
            float wv[8] = {wa.x, wa.y, wa.z, wa.w, wb.x, wb.y, wb.z, wb.w};
#pragma unroll
            for (int i = 0; i < 4; ++i)
#pragma unroll
                for (int j = 0; j < 8; ++j)
                    acc[i][j] += xv[i] * wv[j];
        }
        if (kp < 7) {
            WRITE(cur ^ 1);            // safe: cur^1 readers passed last barrier
            __syncthreads();
        }
    }

#pragma unroll
    for (int i = 0; i < 4; ++i) {
        int rg = row0 + r0 + i;
        if (rg < NN) {
            *(float4*)(out + (size_t)rg * D + c0) =
                make_float4(acc[i][0], acc[i][1], acc[i][2], acc[i][3]);
            *(float4*)(out + (size_t)rg * D + c0 + 64) =
                make_float4(acc[i][4], acc[i][5], acc[i][6], acc[i][7]);
        }
    }
}

// ---------------- hist (standalone, first) ----------------
__global__ __launch_bounds__(256) void k_hist(const int* __restrict__ dst,
                                              int* __restrict__ deg) {
    int e = blockIdx.x * 256 + threadIdx.x;
    if (e < NE) atomicAdd(&deg[dst[e]], 1);
}

// ---------------- K2: scanA (+dinv fused) || bounds ----------------
__global__ __launch_bounds__(256) void k_scanA(const int* __restrict__ deg,
                                               float* __restrict__ dinv,
                                               int* __restrict__ row_ptr,
                                               int* __restrict__ bsum,
                                               const int* __restrict__ batch,
                                               int* __restrict__ gstart) {
    int b = blockIdx.x, tid = threadIdx.x;
    if (b >= NB) {
        int g = (b - NB) * 256 + tid;
        if (g > NG) return;
        if (g == NG) { gstart[NG] = NN; return; }
        int lo = 0, hi = NN;               // first v with batch[v] >= g
        while (lo < hi) {
            int mid = (lo + hi) >> 1;
            if (batch[mid] < g) lo = mid + 1; else hi = mid;
        }
        gstart[g] = lo;
        return;
    }
    __shared__ int sh[256];
    int base = b * SCAN_CHUNK + tid * 8;
    int loc[8];
    int s = 0;
#pragma unroll
    for (int j = 0; j < 8; ++j) {
        int i = base + j;
        int d = (i < NN) ? deg[i] : 0;
        if (i < NN) dinv[i] = rsqrtf((float)(d + 1));   // +1 self-loop
        loc[j] = s;
        s += d;
    }
    sh[tid] = s;
    __syncthreads();
    for (int off = 1; off < 256; off <<= 1) {
        int v = (tid >= off) ? sh[tid - off] : 0;
        __syncthreads();
        sh[tid] += v;
        __syncthreads();
    }
    int excl = (tid == 0) ? 0 : sh[tid - 1];
#pragma unroll
    for (int j = 0; j < 8; ++j) {
        int i = base + j;
        if (i < NN) row_ptr[i] = excl + loc[j];
    }
    if (tid == 255) bsum[b] = sh[255];
}

// ---------------- K3: scanC with inline block-sum prefix ----------------
__global__ __launch_bounds__(256) void k_scanC(int* __restrict__ row_ptr,
                                               const int* __restrict__ bsum,
                                               int* __restrict__ fill) {
    __shared__ int sb[64];
    int tid = threadIdx.x;
    if (tid < NB) sb[tid] = bsum[tid];
    __syncthreads();
    int chunk = (blockIdx.x * 256) / SCAN_CHUNK;
    int pre = 0;
    for (int b = 0; b < chunk; ++b) pre += sb[b];   // uniform LDS broadcast
    int i = blockIdx.x * 256 + tid;
    if (i < NN) {
        int r = row_ptr[i] + pre;
        row_ptr[i] = r;
        fill[i] = r;
    }
    if (i == 0) row_ptr[NN] = NE;
}

// ---------------- K4: gemm1 (blocks 0..GEMM_BLKS) || CSR fill (rest) ----------------
__global__ __launch_bounds__(256) void k_gemm1_fill(const float* __restrict__ x,
                                                    const float* __restrict__ W1,
                                                    float* __restrict__ bufA,
                                                    const int* __restrict__ src,
                                                    const int* __restrict__ dst,
                                                    const float* __restrict__ dinv,
                                                    int* __restrict__ fillc,
                                                    int2* __restrict__ csr) {
    int b = blockIdx.x;
    if (b < GEMM_BLKS) {
        gemm_body(x, W1, nullptr, 0, bufA, b);
    } else {
        int e = (b - GEMM_BLKS) * 256 + threadIdx.x;
        if (e < NE) {
            int s = src[e], d = dst[e];
            float nrm = dinv[s] * dinv[d];
            int pos = atomicAdd(&fillc[d], 1);
            csr[pos] = make_int2(s, __float_as_int(nrm));
        }
    }
}

// ---------------- layer-2 GEMM ----------------
__global__ __launch_bounds__(256) void k_gemm(const float* __restrict__ in,
                                              const float* __restrict__ W,
                                              const float* __restrict__ bias_in,
                                              float* __restrict__ out) {
    gemm_body(in, W, bias_in, 1, out, blockIdx.x);
}

// ---------------- gather: agg[v] = h[v]*dinv[v]^2 + sum_in h[s]*norm ----------------
__global__ __launch_bounds__(256) void k_gather(const float* __restrict__ h,
                                                const int* __restrict__ row_ptr,
                                                const int2* __restrict__ csr,
                                                const float* __restrict__ dinv,
                                                float* __restrict__ agg) {
    int t = blockIdx.x * 256 + threadIdx.x;   // NN*32 threads
    int v = t >> 5;
    if (v >= NN) return;
    int c = (t & 31) * 4;

    float di = dinv[v];
    float sl = di * di;
    float4 acc = *(const float4*)(h + (size_t)v * D + c);
    acc.x *= sl; acc.y *= sl; acc.z *= sl; acc.w *= sl;

    int p   = row_ptr[v];
    int end = row_ptr[v + 1];
    for (; p + 3 < end; p += 4) {
        int2 e0 = csr[p], e1 = csr[p + 1], e2 = csr[p + 2], e3 = csr[p + 3];
        float n0 = __int_as_float(e0.y);
        float n1 = __int_as_float(e1.y);
        float n2 = __int_as_float(e2.y);
        float n3 = __int_as_float(e3.y);
        float4 h0 = *(const float4*)(h + (size_t)e0.x * D + c);
        float4 h1 = *(const float4*)(h + (size_t)e1.x * D + c);
        float4 h2 = *(const float4*)(h + (size_t)e2.x * D + c);
        float4 h3 = *(const float4*)(h + (size_t)e3.x * D + c);
        acc.x += h0.x * n0; acc.y += h0.y * n0; acc.z += h0.z * n0; acc.w += h0.w * n0;
        acc.x += h1.x * n1; acc.y += h1.y * n1; acc.z += h1.z * n1; acc.w += h1.w * n1;
        acc.x += h2.x * n2; acc.y += h2.y * n2; acc.z += h2.z * n2; acc.w += h2.w * n2;
        acc.x += h3.x * n3; acc.y += h3.y * n3; acc.z += h3.z * n3; acc.w += h3.w * n3;
    }
    for (; p < end; ++p) {
        int2 e0 = csr[p];
        float n0 = __int_as_float(e0.y);
        float4 h0 = *(const float4*)(h + (size_t)e0.x * D + c);
        acc.x += h0.x * n0; acc.y += h0.y * n0; acc.z += h0.z * n0; acc.w += h0.w * n0;
    }
    *(float4*)(agg + (size_t)v * D + c) = acc;
}

// ---------------- fused pool + classifier (2 graphs per 256-thread block) ----------------
__global__ __launch_bounds__(256) void k_poolcls(const float* __restrict__ agg,
                                                 const float* __restrict__ b2,
                                                 const int* __restrict__ gstart,
                                                 const float* __restrict__ Wc,
                                                 const float* __restrict__ bc,
                                                 float* __restrict__ out) {
    int half = threadIdx.x >> 7;        // 0 or 1
    int c    = threadIdx.x & 127;
    int g    = blockIdx.x * 2 + half;
    int v0 = gstart[g], v1 = gstart[g + 1];
    float bb = b2[c];
    float acc = 0.f;
    int v = v0;
    for (; v + 7 < v1; v += 8) {            // 8-deep for latency
        float x0 = agg[(size_t)(v + 0) * D + c];
        float x1 = agg[(size_t)(v + 1) * D + c];
        float x2 = agg[(size_t)(v + 2) * D + c];
        float x3 = agg[(size_t)(v + 3) * D + c];
        float x4 = agg[(size_t)(v + 4) * D + c];
        float x5 = agg[(size_t)(v + 5) * D + c];
        float x6 = agg[(size_t)(v + 6) * D + c];
        float x7 = agg[(size_t)(v + 7) * D + c];
        acc += fmaxf(x0 + bb, 0.f) + fmaxf(x1 + bb, 0.f)
             + fmaxf(x2 + bb, 0.f) + fmaxf(x3 + bb, 0.f)
             + fmaxf(x4 + bb, 0.f) + fmaxf(x5 + bb, 0.f)
             + fmaxf(x6 + bb, 0.f) + fmaxf(x7 + bb, 0.f);
    }
    for (; v < v1; ++v)
        acc += fmaxf(agg[(size_t)v * D + c] + bb, 0.f);

    float inv = 1.0f / fmaxf((float)(v1 - v0), 1.0f);
    float pv = acc * inv;

    __shared__ float red[2][2][128];
    red[half][0][c] = pv * Wc[c * 2 + 0];
    red[half][1][c] = pv * Wc[c * 2 + 1];
    __syncthreads();
    if (c < 64) {
        float s = red[half][0][c] + red[half][0][c + 64];
        for (int off = 32; off; off >>= 1) s += __shfl_down(s, off);
        if (c == 0) out[g * 2 + 0] = s + bc[0];
    } else {
        int l = c - 64;
        float s = red[half][1][l] + red[half][1][l + 64];
        for (int off = 32; off; off >>= 1) s += __shfl_down(s, off);
        if (l == 0) out[g * 2 + 1] = s + bc[1];
    }
}

extern "C" void kernel_launch(void* const* d_in, const int* in_sizes, int n_in,
                              void* d_out, int out_size, void* d_ws, size_t ws_size,
                              hipStream_t stream) {
    const float* x     = (const float*)d_in[0];
    const int*   ei    = (const int*)d_in[1];
    const int*   batch = (const int*)d_in[2];
    const float* W1    = (const float*)d_in[3];
    const float* b1    = (const float*)d_in[4];
    const float* W2    = (const float*)d_in[5];
    const float* b2    = (const float*)d_in[6];
    const float* Wc    = (const float*)d_in[7];
    const float* bc    = (const float*)d_in[8];
    float* out = (float*)d_out;

    const int* src = ei;            // edge_index[0]
    const int* dst = ei + NE;       // edge_index[1]

    char* p = (char*)d_ws;
    int*   deg_i   = (int*)p;    p += 100352 * 4;
    float* dinv    = (float*)p;  p += 100352 * 4;
    int*   row_ptr = (int*)p;    p += 100352 * 4;   // NN+1 fits
    int*   fillc   = (int*)p;    p += 100352 * 4;
    int*   bsum    = (int*)p;    p += 256 * 4;
    int*   gstart  = (int*)p;    p += 1056 * 4;     // NG+1
    int2*  csr     = (int2*)p;   p += (size_t)NE * 8;
    float* bufA    = (float*)p;  p += (size_t)NN * D * 4;
    float* bufB    = (float*)p;  p += (size_t)NN * D * 4;

    hipMemsetAsync(deg_i, 0, 100352 * 4, stream);

    // CSR build: hist exposed (small); fill hidden under layer-1 GEMM
    k_hist <<<HIST_BLKS, 256, 0, stream>>>(dst, deg_i);
    k_scanA<<<NB + BOUNDS_BLKS, 256, 0, stream>>>(deg_i, dinv, row_ptr, bsum, batch, gstart);
    k_scanC<<<(NN + 255) / 256, 256, 0, stream>>>(row_ptr, bsum, fillc);

    // K4: layer-1 GEMM || CSR fill
    k_gemm1_fill<<<GEMM_BLKS + HIST_BLKS, 256, 0, stream>>>(x, W1, bufA, src, dst,
                                                            dinv, fillc, csr);
    // layer 1 gather
    k_gather<<<NN * 32 / 256, 256, 0, stream>>>(bufA, row_ptr, csr, dinv, bufB);

    // layer 2 (bias1+relu fused into gemm load)
    k_gemm<<<GEMM_BLKS, 256, 0, stream>>>(bufB, W2, b1, bufA);
    k_gather<<<NN * 32 / 256, 256, 0, stream>>>(bufA, row_ptr, csr, dinv, bufB);

    // fused pooling (bias2+relu) + classifier, 2 graphs/block
    k_poolcls<<<NG / 2, 256, 0, stream>>>(bufB, b2, gstart, Wc, bc, out);
}

// Round 13
// 490.399 us; speedup vs baseline: 1.1422x; 1.1187x over previous
//
#include <hip/hip_runtime.h>

#define NN 100000
#define NE 1600000
#define D 128
#define NG 1024
#define SCAN_CHUNK 2048
#define NB ((NN + SCAN_CHUNK - 1) / SCAN_CHUNK)   // 49
#define GEMM_BLKS ((NN + 63) / 64)                // 1563
#define HIST_BLKS ((NE + 255) / 256)              // 6250
#define BOUNDS_BLKS 5                             // 5*256 >= NG+1

// ---------------- GEMM body: out[r][c] = sum_k act(in[r][k]) * W[k][c] ----------------
// 64x128 tile, K in 8 double-buffered panels of 16. 256 thr, per-thread 4x8
// (VGPR ~84 -> 4+ blocks/CU). Single barrier per panel: WRITE targets cur^1,
// whose readers all passed the previous barrier.
__device__ __forceinline__ void gemm_body(const float* __restrict__ in,
                                          const float* __restrict__ W,
                                          const float* __restrict__ bias_in,
                                          int relu_in,
                                          float* __restrict__ out,
                                          int blk) {
    __shared__ float xs[2][16][68];    // [buf][k][row] transposed panel (2-way max)
    __shared__ float ws[2][16][128];   // [buf][k][col] lane-sequential float4s

    int tid  = threadIdx.x;
    int row0 = blk * 64;

    int srow = tid >> 2;               // x staging row 0..63
    int skq  = (tid & 3) * 4;          // k-quad
    int wkr  = tid >> 5;               // W staging k-row
    int wcq  = (tid & 31) * 4;         // W col quad
    int tx = tid & 15, ty = tid >> 4;
    int r0 = ty * 4, c0 = tx * 4;      // cols c0 and c0+64

    float4 lx, lw0, lw1;

    auto LOAD = [&](int kp) {
        int k0 = kp * 16;
        int rg = row0 + srow; if (rg >= NN) rg = NN - 1;
        lx  = *(const float4*)(in + (size_t)rg * D + k0 + skq);
        lw0 = *(const float4*)(W + (size_t)(k0 + wkr) * D + wcq);
        lw1 = *(const float4*)(W + (size_t)(k0 + 8 + wkr) * D + wcq);
        if (relu_in) {
            float4 bb = *(const float4*)(bias_in + k0 + skq);
            lx.x = fmaxf(lx.x + bb.x, 0.f);
            lx.y = fmaxf(lx.y + bb.y, 0.f);
            lx.z = fmaxf(lx.z + bb.z, 0.f);
            lx.w = fmaxf(lx.w + bb.w, 0.f);
        }
    };
    auto WRITE = [&](int buf) {
        xs[buf][skq + 0][srow] = lx.x;
        xs[buf][skq + 1][srow] = lx.y;
        xs[buf][skq + 2][srow] = lx.z;
        xs[buf][skq + 3][srow] = lx.w;
        *(float4*)&ws[buf][wkr][wcq]     = lw0;
        *(float4*)&ws[buf][wkr + 8][wcq] = lw1;
    };

    float acc[4][8] = {};

    LOAD(0);
    WRITE(0);
    __syncthreads();

    for (int kp = 0; kp < 8; ++kp) {
        int cur = kp & 1;
        if (kp < 7) LOAD(kp + 1);      // global loads in flight over compute
#pragma unroll
        for (int kk = 0; kk < 16; ++kk) {
            float4 xa = *(const float4*)&xs[cur][kk][r0];
            float4 wa = *(const float4*)&ws[cur][kk][c0];
            float4 wb = *(const float4*)&ws[cur][kk][c0 + 64];
            float xv[4] = {xa.x, xa.y, xa.z, xa.w};
            float wv[8] = {wa.x, wa.y, wa.z, wa.w, wb.x, wb.y, wb.z, wb.w};
#pragma unroll
            for (int i = 0; i < 4; ++i)
#pragma unroll
                for (int j = 0; j < 8; ++j)
                    acc[i][j] += xv[i] * wv[j];
        }
        if (kp < 7) {
            WRITE(cur ^ 1);            // safe: cur^1 readers passed last barrier
            __syncthreads();
        }
    }

#pragma unroll
    for (int i = 0; i < 4; ++i) {
        int rg = row0 + r0 + i;
        if (rg < NN) {
            *(float4*)(out + (size_t)rg * D + c0) =
                make_float4(acc[i][0], acc[i][1], acc[i][2], acc[i][3]);
            *(float4*)(out + (size_t)rg * D + c0 + 64) =
                make_float4(acc[i][4], acc[i][5], acc[i][6], acc[i][7]);
        }
    }
}

// ---------------- K1: gemm1 (blocks 0..GEMM_BLKS) || hist (rest) ----------------
__global__ __launch_bounds__(256) void k_gemm1_hist(const float* __restrict__ x,
                                                    const float* __restrict__ W1,
                                                    float* __restrict__ bufA,
                                                    const int* __restrict__ dst,
                                                    int* __restrict__ deg) {
    int b = blockIdx.x;
    if (b < GEMM_BLKS) {
        gemm_body(x, W1, nullptr, 0, bufA, b);
    } else {
        int e = (b - GEMM_BLKS) * 256 + threadIdx.x;
        if (e < NE) atomicAdd(&deg[dst[e]], 1);
    }
}

// ---------------- layer-2 GEMM ----------------
__global__ __launch_bounds__(256) void k_gemm(const float* __restrict__ in,
                                              const float* __restrict__ W,
                                              const float* __restrict__ bias_in,
                                              float* __restrict__ out) {
    gemm_body(in, W, bias_in, 1, out, blockIdx.x);
}

// ---------------- K2: scanA (+dinv fused) || bounds ----------------
__global__ __launch_bounds__(256) void k_scanA(const int* __restrict__ deg,
                                               float* __restrict__ dinv,
                                               int* __restrict__ row_ptr,
                                               int* __restrict__ bsum,
                                               const int* __restrict__ batch,
                                               int* __restrict__ gstart) {
    int b = blockIdx.x, tid = threadIdx.x;
    if (b >= NB) {
        int g = (b - NB) * 256 + tid;
        if (g > NG) return;
        if (g == NG) { gstart[NG] = NN; return; }
        int lo = 0, hi = NN;               // first v with batch[v] >= g
        while (lo < hi) {
            int mid = (lo + hi) >> 1;
            if (batch[mid] < g) lo = mid + 1; else hi = mid;
        }
        gstart[g] = lo;
        return;
    }
    __shared__ int sh[256];
    int base = b * SCAN_CHUNK + tid * 8;
    int loc[8];
    int s = 0;
#pragma unroll
    for (int j = 0; j < 8; ++j) {
        int i = base + j;
        int d = (i < NN) ? deg[i] : 0;
        if (i < NN) dinv[i] = rsqrtf((float)(d + 1));   // +1 self-loop
        loc[j] = s;
        s += d;
    }
    sh[tid] = s;
    __syncthreads();
    for (int off = 1; off < 256; off <<= 1) {
        int v = (tid >= off) ? sh[tid - off] : 0;
        __syncthreads();
        sh[tid] += v;
        __syncthreads();
    }
    int excl = (tid == 0) ? 0 : sh[tid - 1];
#pragma unroll
    for (int j = 0; j < 8; ++j) {
        int i = base + j;
        if (i < NN) row_ptr[i] = excl + loc[j];
    }
    if (tid == 255) bsum[b] = sh[255];
}

// ---------------- K3: scanC with inline block-sum prefix ----------------
__global__ __launch_bounds__(256) void k_scanC(int* __restrict__ row_ptr,
                                               const int* __restrict__ bsum,
                                               int* __restrict__ fill) {
    __shared__ int sb[64];
    int tid = threadIdx.x;
    if (tid < NB) sb[tid] = bsum[tid];
    __syncthreads();
    int chunk = (blockIdx.x * 256) / SCAN_CHUNK;
    int pre = 0;
    for (int b = 0; b < chunk; ++b) pre += sb[b];   // uniform LDS broadcast
    int i = blockIdx.x * 256 + tid;
    if (i < NN) {
        int r = row_ptr[i] + pre;
        row_ptr[i] = r;
        fill[i] = r;
    }
    if (i == 0) row_ptr[NN] = NE;
}

// ---------------- CSR fill: csr[pos] = {src, norm} ----------------
__global__ __launch_bounds__(256) void k_fill(const int* __restrict__ src,
                                              const int* __restrict__ dst,
                                              const float* __restrict__ dinv,
                                              int* __restrict__ fill,
                                              int2* __restrict__ csr) {
    int e = blockIdx.x * 256 + threadIdx.x;
    if (e >= NE) return;
    int s = src[e], d = dst[e];
    float nrm = dinv[s] * dinv[d];
    int pos = atomicAdd(&fill[d], 1);
    csr[pos] = make_int2(s, __float_as_int(nrm));
}

// ---------------- gather: agg[v] = h[v]*dinv[v]^2 + sum_in h[s]*norm ----------------
__global__ __launch_bounds__(256) void k_gather(const float* __restrict__ h,
                                                const int* __restrict__ row_ptr,
                                                const int2* __restrict__ csr,
                                                const float* __restrict__ dinv,
                                                float* __restrict__ agg) {
    int t = blockIdx.x * 256 + threadIdx.x;   // NN*32 threads
    int v = t >> 5;
    if (v >= NN) return;
    int c = (t & 31) * 4;

    float di = dinv[v];
    float sl = di * di;
    float4 acc = *(const float4*)(h + (size_t)v * D + c);
    acc.x *= sl; acc.y *= sl; acc.z *= sl; acc.w *= sl;

    int p   = row_ptr[v];
    int end = row_ptr[v + 1];
    for (; p + 3 < end; p += 4) {
        int2 e0 = csr[p], e1 = csr[p + 1], e2 = csr[p + 2], e3 = csr[p + 3];
        float n0 = __int_as_float(e0.y);
        float n1 = __int_as_float(e1.y);
        float n2 = __int_as_float(e2.y);
        float n3 = __int_as_float(e3.y);
        float4 h0 = *(const float4*)(h + (size_t)e0.x * D + c);
        float4 h1 = *(const float4*)(h + (size_t)e1.x * D + c);
        float4 h2 = *(const float4*)(h + (size_t)e2.x * D + c);
        float4 h3 = *(const float4*)(h + (size_t)e3.x * D + c);
        acc.x += h0.x * n0; acc.y += h0.y * n0; acc.z += h0.z * n0; acc.w += h0.w * n0;
        acc.x += h1.x * n1; acc.y += h1.y * n1; acc.z += h1.z * n1; acc.w += h1.w * n1;
        acc.x += h2.x * n2; acc.y += h2.y * n2; acc.z += h2.z * n2; acc.w += h2.w * n2;
        acc.x += h3.x * n3; acc.y += h3.y * n3; acc.z += h3.z * n3; acc.w += h3.w * n3;
    }
    for (; p < end; ++p) {
        int2 e0 = csr[p];
        float n0 = __int_as_float(e0.y);
        float4 h0 = *(const float4*)(h + (size_t)e0.x * D + c);
        acc.x += h0.x * n0; acc.y += h0.y * n0; acc.z += h0.z * n0; acc.w += h0.w * n0;
    }
    *(float4*)(agg + (size_t)v * D + c) = acc;
}

// ---------------- fused pool + classifier (block per graph) ----------------
__global__ __launch_bounds__(128) void k_poolcls(const float* __restrict__ agg,
                                                 const float* __restrict__ b2,
                                                 const int* __restrict__ gstart,
                                                 const float* __restrict__ Wc,
                                                 const float* __restrict__ bc,
                                                 float* __restrict__ out) {
    int g = blockIdx.x;
    int c = threadIdx.x;
    int v0 = gstart[g], v1 = gstart[g + 1];
    float bb = b2[c];
    float acc = 0.f;
    int v = v0;
    for (; v + 7 < v1; v += 8) {            // 8-deep for latency
        float x0 = agg[(size_t)(v + 0) * D + c];
        float x1 = agg[(size_t)(v + 1) * D + c];
        float x2 = agg[(size_t)(v + 2) * D + c];
        float x3 = agg[(size_t)(v + 3) * D + c];
        float x4 = agg[(size_t)(v + 4) * D + c];
        float x5 = agg[(size_t)(v + 5) * D + c];
        float x6 = agg[(size_t)(v + 6) * D + c];
        float x7 = agg[(size_t)(v + 7) * D + c];
        acc += fmaxf(x0 + bb, 0.f) + fmaxf(x1 + bb, 0.f)
             + fmaxf(x2 + bb, 0.f) + fmaxf(x3 + bb, 0.f)
             + fmaxf(x4 + bb, 0.f) + fmaxf(x5 + bb, 0.f)
             + fmaxf(x6 + bb, 0.f) + fmaxf(x7 + bb, 0.f);
    }
    for (; v < v1; ++v)
        acc += fmaxf(agg[(size_t)v * D + c] + bb, 0.f);

    float inv = 1.0f / fmaxf((float)(v1 - v0), 1.0f);
    float pv = acc * inv;

    __shared__ float red[2][128];
    red[0][c] = pv * Wc[c * 2 + 0];
    red[1][c] = pv * Wc[c * 2 + 1];
    __syncthreads();
    if (c < 64) {
        float s = red[0][c] + red[0][c + 64];
        for (int off = 32; off; off >>= 1) s += __shfl_down(s, off);
        if (c == 0) out[g * 2 + 0] = s + bc[0];
    } else {
        int l = c - 64;
        float s = red[1][l] + red[1][l + 64];
        for (int off = 32; off; off >>= 1) s += __shfl_down(s, off);
        if (l == 0) out[g * 2 + 1] = s + bc[1];
    }
}

extern "C" void kernel_launch(void* const* d_in, const int* in_sizes, int n_in,
                              void* d_out, int out_size, void* d_ws, size_t ws_size,
                              hipStream_t stream) {
    const float* x     = (const float*)d_in[0];
    const int*   ei    = (const int*)d_in[1];
    const int*   batch = (const int*)d_in[2];
    const float* W1    = (const float*)d_in[3];
    const float* b1    = (const float*)d_in[4];
    const float* W2    = (const float*)d_in[5];
    const float* b2    = (const float*)d_in[6];
    const float* Wc    = (const float*)d_in[7];
    const float* bc    = (const float*)d_in[8];
    float* out = (float*)d_out;

    const int* src = ei;            // edge_index[0]
    const int* dst = ei + NE;       // edge_index[1]

    char* p = (char*)d_ws;
    int*   deg_i   = (int*)p;    p += 100352 * 4;
    float* dinv    = (float*)p;  p += 100352 * 4;
    int*   row_ptr = (int*)p;    p += 100352 * 4;   // NN+1 fits
    int*   fillc   = (int*)p;    p += 100352 * 4;
    int*   bsum    = (int*)p;    p += 256 * 4;
    int*   gstart  = (int*)p;    p += 1056 * 4;     // NG+1
    int2*  csr     = (int2*)p;   p += (size_t)NE * 8;
    float* bufA    = (float*)p;  p += (size_t)NN * D * 4;
    float* bufB    = (float*)p;  p += (size_t)NN * D * 4;

    hipMemsetAsync(deg_i, 0, 100352 * 4, stream);

    // K1: layer-1 GEMM || degree histogram
    k_gemm1_hist<<<GEMM_BLKS + HIST_BLKS, 256, 0, stream>>>(x, W1, bufA, dst, deg_i);
    // K2: scan phase A (+dinv) || graph bounds
    k_scanA<<<NB + BOUNDS_BLKS, 256, 0, stream>>>(deg_i, dinv, row_ptr, bsum, batch, gstart);
    // K3: scan finalize
    k_scanC<<<(NN + 255) / 256, 256, 0, stream>>>(row_ptr, bsum, fillc);
    // K4: CSR fill
    k_fill<<<HIST_BLKS, 256, 0, stream>>>(src, dst, dinv, fillc, csr);

    // layer 1 gather
    k_gather<<<NN * 32 / 256, 256, 0, stream>>>(bufA, row_ptr, csr, dinv, bufB);

    // layer 2 (bias1+relu fused into gemm load)
    k_gemm<<<GEMM_BLKS, 256, 0, stream>>>(bufB, W2, b1, bufA);
    k_gather<<<NN * 32 / 256, 256, 0, stream>>>(bufA, row_ptr, csr, dinv, bufB);

    // fused pooling (bias2+relu) + classifier
    k_poolcls<<<NG, 128, 0, stream>>>(bufB, b2, gstart, Wc, bc, out);
}

// Round 14
// 377.717 us; speedup vs baseline: 1.4829x; 1.2983x over previous
//
#include <hip/hip_runtime.h>

#define NN 100000
#define NE 1600000
#define D 128
#define NG 1024
#define SCAN_CHUNK 2048
#define NB ((NN + SCAN_CHUNK - 1) / SCAN_CHUNK)   // 49
#define GEMM_BLKS ((NN + 63) / 64)                // 1563
#define HIST_BLKS ((NE + 255) / 256)              // 6250
#define BOUNDS_BLKS 5                             // 5*256 >= NG+1

typedef _Float16 h4 __attribute__((ext_vector_type(4)));

// ---------------- GEMM body: out[r][c] = sum_k act(in[r][k]) * W[k][c] ----------------
// 64x128 tile, K in 8 double-buffered panels of 16, per-thread 4x8 (VGPR ~84).
// Input TIN = float (layer 1, x) or _Float16 (layer 2, agg1). Output fp16.
// Compute entirely fp32. Single barrier per panel.
template<int RELU, typename TIN>
__device__ __forceinline__ void gemm_body(const TIN* __restrict__ in,
                                          const float* __restrict__ W,
                                          const float* __restrict__ bias_in,
                                          _Float16* __restrict__ out,
                                          int blk) {
    __shared__ float xs[2][16][68];    // [buf][k][row] transposed panel (2-way max)
    __shared__ float ws[2][16][128];   // [buf][k][col] lane-sequential float4s

    int tid  = threadIdx.x;
    int row0 = blk * 64;

    int srow = tid >> 2;               // x staging row 0..63
    int skq  = (tid & 3) * 4;          // k-quad
    int wkr  = tid >> 5;               // W staging k-row
    int wcq  = (tid & 31) * 4;         // W col quad
    int tx = tid & 15, ty = tid >> 4;
    int r0 = ty * 4, c0 = tx * 4;      // cols c0 and c0+64

    float4 lx, lw0, lw1;

    auto LOAD = [&](int kp) {
        int k0 = kp * 16;
        int rg = row0 + srow; if (rg >= NN) rg = NN - 1;
        const TIN* rp = in + (size_t)rg * D + k0 + skq;
        if constexpr (sizeof(TIN) == 4) {
            lx = *(const float4*)rp;
        } else {
            h4 hv = *(const h4*)rp;
            lx = make_float4((float)hv.x, (float)hv.y, (float)hv.z, (float)hv.w);
        }
        lw0 = *(const float4*)(W + (size_t)(k0 + wkr) * D + wcq);
        lw1 = *(const float4*)(W + (size_t)(k0 + 8 + wkr) * D + wcq);
        if (RELU) {
            float4 bb = *(const float4*)(bias_in + k0 + skq);
            lx.x = fmaxf(lx.x + bb.x, 0.f);
            lx.y = fmaxf(lx.y + bb.y, 0.f);
            lx.z = fmaxf(lx.z + bb.z, 0.f);
            lx.w = fmaxf(lx.w + bb.w, 0.f);
        }
    };
    auto WRITE = [&](int buf) {
        xs[buf][skq + 0][srow] = lx.x;
        xs[buf][skq + 1][srow] = lx.y;
        xs[buf][skq + 2][srow] = lx.z;
        xs[buf][skq + 3][srow] = lx.w;
        *(float4*)&ws[buf][wkr][wcq]     = lw0;
        *(float4*)&ws[buf][wkr + 8][wcq] = lw1;
    };

    float acc[4][8] = {};

    LOAD(0);
    WRITE(0);
    __syncthreads();

    for (int kp = 0; kp < 8; ++kp) {
        int cur = kp & 1;
        if (kp < 7) LOAD(kp + 1);      // global loads in flight over compute
#pragma unroll
        for (int kk = 0; kk < 16; ++kk) {
            float4 xa = *(const float4*)&xs[cur][kk][r0];
            float4 wa = *(const float4*)&ws[cur][kk][c0];
            float4 wb = *(const float4*)&ws[cur][kk][c0 + 64];
            float xv[4] = {xa.x, xa.y, xa.z, xa.w};
            float wv[8] = {wa.x, wa.y, wa.z, wa.w, wb.x, wb.y, wb.z, wb.w};
#pragma unroll
            for (int i = 0; i < 4; ++i)
#pragma unroll
                for (int j = 0; j < 8; ++j)
                    acc[i][j] += xv[i] * wv[j];
        }
        if (kp < 7) {
            WRITE(cur ^ 1);            // safe: cur^1 readers passed last barrier
            __syncthreads();
        }
    }

#pragma unroll
    for (int i = 0; i < 4; ++i) {
        int rg = row0 + r0 + i;
        if (rg < NN) {
            h4 o0 = {(_Float16)acc[i][0], (_Float16)acc[i][1],
                     (_Float16)acc[i][2], (_Float16)acc[i][3]};
            h4 o1 = {(_Float16)acc[i][4], (_Float16)acc[i][5],
                     (_Float16)acc[i][6], (_Float16)acc[i][7]};
            *(h4*)(out + (size_t)rg * D + c0)      = o0;
            *(h4*)(out + (size_t)rg * D + c0 + 64) = o1;
        }
    }
}

// ---------------- K1: gemm1 (blocks 0..GEMM_BLKS) || hist (rest) ----------------
__global__ __launch_bounds__(256) void k_gemm1_hist(const float* __restrict__ x,
                                                    const float* __restrict__ W1,
                                                    _Float16* __restrict__ bufA,
                                                    const int* __restrict__ dst,
                                                    int* __restrict__ deg) {
    int b = blockIdx.x;
    if (b < GEMM_BLKS) {
        gemm_body<0, float>(x, W1, nullptr, bufA, b);
    } else {
        int e = (b - GEMM_BLKS) * 256 + threadIdx.x;
        if (e < NE) atomicAdd(&deg[dst[e]], 1);
    }
}

// ---------------- layer-2 GEMM (fp16 in, relu+bias fused) ----------------
__global__ __launch_bounds__(256) void k_gemm(const _Float16* __restrict__ in,
                                              const float* __restrict__ W,
                                              const float* __restrict__ bias_in,
                                              _Float16* __restrict__ out) {
    gemm_body<1, _Float16>(in, W, bias_in, out, blockIdx.x);
}

// ---------------- K2: scanA (+dinv fused) || bounds ----------------
__global__ __launch_bounds__(256) void k_scanA(const int* __restrict__ deg,
                                               float* __restrict__ dinv,
                                               int* __restrict__ row_ptr,
                                               int* __restrict__ bsum,
                                               const int* __restrict__ batch,
                                               int* __restrict__ gstart) {
    int b = blockIdx.x, tid = threadIdx.x;
    if (b >= NB) {
        int g = (b - NB) * 256 + tid;
        if (g > NG) return;
        if (g == NG) { gstart[NG] = NN; return; }
        int lo = 0, hi = NN;               // first v with batch[v] >= g
        while (lo < hi) {
            int mid = (lo + hi) >> 1;
            if (batch[mid] < g) lo = mid + 1; else hi = mid;
        }
        gstart[g] = lo;
        return;
    }
    __shared__ int sh[256];
    int base = b * SCAN_CHUNK + tid * 8;
    int loc[8];
    int s = 0;
#pragma unroll
    for (int j = 0; j < 8; ++j) {
        int i = base + j;
        int d = (i < NN) ? deg[i] : 0;
        if (i < NN) dinv[i] = rsqrtf((float)(d + 1));   // +1 self-loop
        loc[j] = s;
        s += d;
    }
    sh[tid] = s;
    __syncthreads();
    for (int off = 1; off < 256; off <<= 1) {
        int v = (tid >= off) ? sh[tid - off] : 0;
        __syncthreads();
        sh[tid] += v;
        __syncthreads();
    }
    int excl = (tid == 0) ? 0 : sh[tid - 1];
#pragma unroll
    for (int j = 0; j < 8; ++j) {
        int i = base + j;
        if (i < NN) row_ptr[i] = excl + loc[j];
    }
    if (tid == 255) bsum[b] = sh[255];
}

// ---------------- K3: scanC with inline block-sum prefix ----------------
__global__ __launch_bounds__(256) void k_scanC(int* __restrict__ row_ptr,
                                               const int* __restrict__ bsum,
                                               int* __restrict__ fill) {
    __shared__ int sb[64];
    int tid = threadIdx.x;
    if (tid < NB) sb[tid] = bsum[tid];
    __syncthreads();
    int chunk = (blockIdx.x * 256) / SCAN_CHUNK;
    int pre = 0;
    for (int b = 0; b < chunk; ++b) pre += sb[b];   // uniform LDS broadcast
    int i = blockIdx.x * 256 + tid;
    if (i < NN) {
        int r = row_ptr[i] + pre;
        row_ptr[i] = r;
        fill[i] = r;
    }
    if (i == 0) row_ptr[NN] = NE;
}

// ---------------- CSR fill: csr[pos] = {src, norm} ----------------
__global__ __launch_bounds__(256) void k_fill(const int* __restrict__ src,
                                              const int* __restrict__ dst,
                                              const float* __restrict__ dinv,
                                              int* __restrict__ fill,
                                              int2* __restrict__ csr) {
    int e = blockIdx.x * 256 + threadIdx.x;
    if (e >= NE) return;
    int s = src[e], d = dst[e];
    float nrm = dinv[s] * dinv[d];
    int pos = atomicAdd(&fill[d], 1);
    csr[pos] = make_int2(s, __float_as_int(nrm));
}

// ---------------- gather: agg[v] = h[v]*dinv[v]^2 + sum_in h[s]*norm ----------------
// fp16 h rows (256 B), fp32 accumulate, fp16 agg out.
__global__ __launch_bounds__(256) void k_gather(const _Float16* __restrict__ hh,
                                                const int* __restrict__ row_ptr,
                                                const int2* __restrict__ csr,
                                                const float* __restrict__ dinv,
                                                _Float16* __restrict__ agg) {
    int t = blockIdx.x * 256 + threadIdx.x;   // NN*32 threads
    int v = t >> 5;
    if (v >= NN) return;
    int c = (t & 31) * 4;

    float di = dinv[v];
    float sl = di * di;
    h4 hv = *(const h4*)(hh + (size_t)v * D + c);
    float4 acc = make_float4((float)hv.x * sl, (float)hv.y * sl,
                             (float)hv.z * sl, (float)hv.w * sl);

    int p   = row_ptr[v];
    int end = row_ptr[v + 1];
    for (; p + 3 < end; p += 4) {
        int2 e0 = csr[p], e1 = csr[p + 1], e2 = csr[p + 2], e3 = csr[p + 3];
        float n0 = __int_as_float(e0.y);
        float n1 = __int_as_float(e1.y);
        float n2 = __int_as_float(e2.y);
        float n3 = __int_as_float(e3.y);
        h4 g0 = *(const h4*)(hh + (size_t)e0.x * D + c);
        h4 g1 = *(const h4*)(hh + (size_t)e1.x * D + c);
        h4 g2 = *(const h4*)(hh + (size_t)e2.x * D + c);
        h4 g3 = *(const h4*)(hh + (size_t)e3.x * D + c);
        acc.x += (float)g0.x * n0; acc.y += (float)g0.y * n0;
        acc.z += (float)g0.z * n0; acc.w += (float)g0.w * n0;
        acc.x += (float)g1.x * n1; acc.y += (float)g1.y * n1;
        acc.z += (float)g1.z * n1; acc.w += (float)g1.w * n1;
        acc.x += (float)g2.x * n2; acc.y += (float)g2.y * n2;
        acc.z += (float)g2.z * n2; acc.w += (float)g2.w * n2;
        acc.x += (float)g3.x * n3; acc.y += (float)g3.y * n3;
        acc.z += (float)g3.z * n3; acc.w += (float)g3.w * n3;
    }
    for (; p < end; ++p) {
        int2 e0 = csr[p];
        float n0 = __int_as_float(e0.y);
        h4 g0 = *(const h4*)(hh + (size_t)e0.x * D + c);
        acc.x += (float)g0.x * n0; acc.y += (float)g0.y * n0;
        acc.z += (float)g0.z * n0; acc.w += (float)g0.w * n0;
    }
    h4 ov = {(_Float16)acc.x, (_Float16)acc.y, (_Float16)acc.z, (_Float16)acc.w};
    *(h4*)(agg + (size_t)v * D + c) = ov;
}

// ---------------- fused pool + classifier (block per graph) ----------------
__global__ __launch_bounds__(128) void k_poolcls(const _Float16* __restrict__ agg,
                                                 const float* __restrict__ b2,
                                                 const int* __restrict__ gstart,
                                                 const float* __restrict__ Wc,
                                                 const float* __restrict__ bc,
                                                 float* __restrict__ out) {
    int g = blockIdx.x;
    int c = threadIdx.x;
    int v0 = gstart[g], v1 = gstart[g + 1];
    float bb = b2[c];
    float acc = 0.f;
    int v = v0;
    for (; v + 7 < v1; v += 8) {            // 8-deep for latency
        float x0 = (float)agg[(size_t)(v + 0) * D + c];
        float x1 = (float)agg[(size_t)(v + 1) * D + c];
        float x2 = (float)agg[(size_t)(v + 2) * D + c];
        float x3 = (float)agg[(size_t)(v + 3) * D + c];
        float x4 = (float)agg[(size_t)(v + 4) * D + c];
        float x5 = (float)agg[(size_t)(v + 5) * D + c];
        float x6 = (float)agg[(size_t)(v + 6) * D + c];
        float x7 = (float)agg[(size_t)(v + 7) * D + c];
        acc += fmaxf(x0 + bb, 0.f) + fmaxf(x1 + bb, 0.f)
             + fmaxf(x2 + bb, 0.f) + fmaxf(x3 + bb, 0.f)
             + fmaxf(x4 + bb, 0.f) + fmaxf(x5 + bb, 0.f)
             + fmaxf(x6 + bb, 0.f) + fmaxf(x7 + bb, 0.f);
    }
    for (; v < v1; ++v)
        acc += fmaxf((float)agg[(size_t)v * D + c] + bb, 0.f);

    float inv = 1.0f / fmaxf((float)(v1 - v0), 1.0f);
    float pv = acc * inv;

    __shared__ float red[2][128];
    red[0][c] = pv * Wc[c * 2 + 0];
    red[1][c] = pv * Wc[c * 2 + 1];
    __syncthreads();
    if (c < 64) {
        float s = red[0][c] + red[0][c + 64];
        for (int off = 32; off; off >>= 1) s += __shfl_down(s, off);
        if (c == 0) out[g * 2 + 0] = s + bc[0];
    } else {
        int l = c - 64;
        float s = red[1][l] + red[1][l + 64];
        for (int off = 32; off; off >>= 1) s += __shfl_down(s, off);
        if (l == 0) out[g * 2 + 1] = s + bc[1];
    }
}

extern "C" void kernel_launch(void* const* d_in, const int* in_sizes, int n_in,
                              void* d_out, int out_size, void* d_ws, size_t ws_size,
                              hipStream_t stream) {
    const float* x     = (const float*)d_in[0];
    const int*   ei    = (const int*)d_in[1];
    const int*   batch = (const int*)d_in[2];
    const float* W1    = (const float*)d_in[3];
    const float* b1    = (const float*)d_in[4];
    const float* W2    = (const float*)d_in[5];
    const float* b2    = (const float*)d_in[6];
    const float* Wc    = (const float*)d_in[7];
    const float* bc    = (const float*)d_in[8];
    float* out = (float*)d_out;

    const int* src = ei;            // edge_index[0]
    const int* dst = ei + NE;       // edge_index[1]

    char* p = (char*)d_ws;
    int*       deg_i   = (int*)p;       p += 100352 * 4;
    float*     dinv    = (float*)p;     p += 100352 * 4;
    int*       row_ptr = (int*)p;       p += 100352 * 4;   // NN+1 fits
    int*       fillc   = (int*)p;       p += 100352 * 4;
    int*       bsum    = (int*)p;       p += 256 * 4;
    int*       gstart  = (int*)p;       p += 1056 * 4;     // NG+1
    int2*      csr     = (int2*)p;      p += (size_t)NE * 8;
    _Float16*  bufA    = (_Float16*)p;  p += (size_t)NN * D * 2;
    _Float16*  bufB    = (_Float16*)p;  p += (size_t)NN * D * 2;

    hipMemsetAsync(deg_i, 0, 100352 * 4, stream);

    // K1: layer-1 GEMM || degree histogram
    k_gemm1_hist<<<GEMM_BLKS + HIST_BLKS, 256, 0, stream>>>(x, W1, bufA, dst, deg_i);
    // K2: scan phase A (+dinv) || graph bounds
    k_scanA<<<NB + BOUNDS_BLKS, 256, 0, stream>>>(deg_i, dinv, row_ptr, bsum, batch, gstart);
    // K3: scan finalize
    k_scanC<<<(NN + 255) / 256, 256, 0, stream>>>(row_ptr, bsum, fillc);
    // K4: CSR fill
    k_fill<<<HIST_BLKS, 256, 0, stream>>>(src, dst, dinv, fillc, csr);

    // layer 1 gather (fp16 h1 -> fp16 agg1)
    k_gather<<<NN * 32 / 256, 256, 0, stream>>>(bufA, row_ptr, csr, dinv, bufB);

    // layer 2 (bias1+relu fused into gemm load, fp16 in/out)
    k_gemm<<<GEMM_BLKS, 256, 0, stream>>>(bufB, W2, b1, bufA);
    k_gather<<<NN * 32 / 256, 256, 0, stream>>>(bufA, row_ptr, csr, dinv, bufB);

    // fused pooling (bias2+relu) + classifier
    k_poolcls<<<NG, 128, 0, stream>>>(bufB, b2, gstart, Wc, bc, out);
}

// Round 15
// 354.519 us; speedup vs baseline: 1.5799x; 1.0654x over previous
//
#include <hip/hip_runtime.h>

#define NN 100000
#define NE 1600000
#define D 128
#define NG 1024
#define SCAN_CHUNK 2048
#define NB ((NN + SCAN_CHUNK - 1) / SCAN_CHUNK)   // 49
#define GEMM_BLKS ((NN + 63) / 64)                // 1563
#define HIST_BLKS ((NE + 255) / 256)              // 6250
#define BOUNDS_BLKS 5                             // 5*256 >= NG+1

typedef _Float16 h4   __attribute__((ext_vector_type(4)));
typedef _Float16 h8   __attribute__((ext_vector_type(8)));
typedef float    f32x4 __attribute__((ext_vector_type(4)));

// ---------------- MFMA GEMM: out[r][c] = (fp16)sum_k act(in[r][k]) * W[k][c] ----------
// 64-row block, 4 waves; each wave: 64 rows x 32 cols, K=128 as 4 chained
// v_mfma_f32_16x16x32_f16 (fp32 accumulate). Wt (pre-transposed fp16 [c][k])
// staged to LDS with +8-half pad -> conflict-free ds_read_b128 B-frags.
// A-frags straight from global: lane l -> row l%16, k = 8*(l/16)+e (16B/lane).
template<int L2>
__device__ __forceinline__ void gemm_mfma(const void* __restrict__ inv,
                                          const _Float16* __restrict__ Wt,
                                          const float* __restrict__ bias,
                                          _Float16* __restrict__ out,
                                          int blk) {
    __shared__ _Float16 wl[128][136];   // [col][k], pad 8 halves (34.8 KB)

    int tid = threadIdx.x;
#pragma unroll
    for (int i = 0; i < 8; ++i) {       // 2048 16B-slots
        int s = tid + i * 256;
        int row = s >> 4, ks = s & 15;
        *(h8*)&wl[row][ks * 8] = *(const h8*)(Wt + row * D + ks * 8);
    }
    __syncthreads();

    int wv = tid >> 6, l = tid & 63;
    int li = l & 15, lg = l >> 4;
    int row0 = blk * 64;
    int colw = wv * 32;

    f32x4 acc[4][2] = {};

    const float*    inf = (const float*)inv;
    const _Float16* inh = (const _Float16*)inv;

#pragma unroll
    for (int kt = 0; kt < 4; ++kt) {
        int kb = kt * 32 + lg * 8;
        float bb[8];
        if (L2) {
#pragma unroll
            for (int e = 0; e < 8; ++e) bb[e] = bias[kb + e];
        }
        h8 a[4];
#pragma unroll
        for (int rt = 0; rt < 4; ++rt) {
            int rg = row0 + rt * 16 + li; if (rg >= NN) rg = NN - 1;
            if (L2) {
                h8 hv = *(const h8*)(inh + (size_t)rg * D + kb);
                h8 av;
#pragma unroll
                for (int e = 0; e < 8; ++e)
                    av[e] = (_Float16)fmaxf((float)hv[e] + bb[e], 0.f);
                a[rt] = av;
            } else {
                float4 f0 = *(const float4*)(inf + (size_t)rg * D + kb);
                float4 f1 = *(const float4*)(inf + (size_t)rg * D + kb + 4);
                h8 av;
                av[0] = (_Float16)f0.x; av[1] = (_Float16)f0.y;
                av[2] = (_Float16)f0.z; av[3] = (_Float16)f0.w;
                av[4] = (_Float16)f1.x; av[5] = (_Float16)f1.y;
                av[6] = (_Float16)f1.z; av[7] = (_Float16)f1.w;
                a[rt] = av;
            }
        }
#pragma unroll
        for (int ct = 0; ct < 2; ++ct) {
            h8 b = *(const h8*)&wl[colw + ct * 16 + li][kb];
#pragma unroll
            for (int rt = 0; rt < 4; ++rt)
                acc[rt][ct] = __builtin_amdgcn_mfma_f32_16x16x32_f16(
                    a[rt], b, acc[rt][ct], 0, 0, 0);
        }
    }

    // D layout: col = lane&15, row = (lane>>4)*4 + e
#pragma unroll
    for (int rt = 0; rt < 4; ++rt)
#pragma unroll
        for (int ct = 0; ct < 2; ++ct)
#pragma unroll
            for (int e = 0; e < 4; ++e) {
                int rg = row0 + rt * 16 + lg * 4 + e;
                if (rg < NN)
                    out[(size_t)rg * D + colw + ct * 16 + li] =
                        (_Float16)acc[rt][ct][e];
            }
}

__global__ __launch_bounds__(256) void k_gemm1(const float* __restrict__ x,
                                               const _Float16* __restrict__ Wt1,
                                               _Float16* __restrict__ out) {
    gemm_mfma<0>(x, Wt1, nullptr, out, blockIdx.x);
}

__global__ __launch_bounds__(256) void k_gemm2(const _Float16* __restrict__ in,
                                               const _Float16* __restrict__ Wt2,
                                               const float* __restrict__ b1,
                                               _Float16* __restrict__ out) {
    gemm_mfma<1>(in, Wt2, b1, out, blockIdx.x);
}

// ---------------- K1: hist || W transpose+fp16 (2 blocks) ----------------
__global__ __launch_bounds__(256) void k_pre(const int* __restrict__ dst,
                                             int* __restrict__ deg,
                                             const float* __restrict__ W1,
                                             const float* __restrict__ W2,
                                             _Float16* __restrict__ Wt1,
                                             _Float16* __restrict__ Wt2) {
    int b = blockIdx.x;
    if (b < HIST_BLKS) {
        int e = b * 256 + threadIdx.x;
        if (e < NE) atomicAdd(&deg[dst[e]], 1);
        return;
    }
    const float*  W  = (b == HIST_BLKS) ? W1 : W2;
    _Float16*     Wt = (b == HIST_BLKS) ? Wt1 : Wt2;
    int t = threadIdx.x;
#pragma unroll
    for (int i = 0; i < 16; ++i) {
        int idx = t + i * 256;              // 4096 float4s
        int k = idx >> 5, c4 = (idx & 31) * 4;
        float4 v = *(const float4*)(W + k * D + c4);
        Wt[(c4 + 0) * D + k] = (_Float16)v.x;
        Wt[(c4 + 1) * D + k] = (_Float16)v.y;
        Wt[(c4 + 2) * D + k] = (_Float16)v.z;
        Wt[(c4 + 3) * D + k] = (_Float16)v.w;
    }
}

// ---------------- K2: scanA (+dinv fused) || bounds ----------------
__global__ __launch_bounds__(256) void k_scanA(const int* __restrict__ deg,
                                               float* __restrict__ dinv,
                                               int* __restrict__ row_ptr,
                                               int* __restrict__ bsum,
                                               const int* __restrict__ batch,
                                               int* __restrict__ gstart) {
    int b = blockIdx.x, tid = threadIdx.x;
    if (b >= NB) {
        int g = (b - NB) * 256 + tid;
        if (g > NG) return;
        if (g == NG) { gstart[NG] = NN; return; }
        int lo = 0, hi = NN;               // first v with batch[v] >= g
        while (lo < hi) {
            int mid = (lo + hi) >> 1;
            if (batch[mid] < g) lo = mid + 1; else hi = mid;
        }
        gstart[g] = lo;
        return;
    }
    __shared__ int sh[256];
    int base = b * SCAN_CHUNK + tid * 8;
    int loc[8];
    int s = 0;
#pragma unroll
    for (int j = 0; j < 8; ++j) {
        int i = base + j;
        int d = (i < NN) ? deg[i] : 0;
        if (i < NN) dinv[i] = rsqrtf((float)(d + 1));   // +1 self-loop
        loc[j] = s;
        s += d;
    }
    sh[tid] = s;
    __syncthreads();
    for (int off = 1; off < 256; off <<= 1) {
        int v = (tid >= off) ? sh[tid - off] : 0;
        __syncthreads();
        sh[tid] += v;
        __syncthreads();
    }
    int excl = (tid == 0) ? 0 : sh[tid - 1];
#pragma unroll
    for (int j = 0; j < 8; ++j) {
        int i = base + j;
        if (i < NN) row_ptr[i] = excl + loc[j];
    }
    if (tid == 255) bsum[b] = sh[255];
}

// ---------------- K3: scanC with inline block-sum prefix ----------------
__global__ __launch_bounds__(256) void k_scanC(int* __restrict__ row_ptr,
                                               const int* __restrict__ bsum,
                                               int* __restrict__ fill) {
    __shared__ int sb[64];
    int tid = threadIdx.x;
    if (tid < NB) sb[tid] = bsum[tid];
    __syncthreads();
    int chunk = (blockIdx.x * 256) / SCAN_CHUNK;
    int pre = 0;
    for (int b = 0; b < chunk; ++b) pre += sb[b];   // uniform LDS broadcast
    int i = blockIdx.x * 256 + tid;
    if (i < NN) {
        int r = row_ptr[i] + pre;
        row_ptr[i] = r;
        fill[i] = r;
    }
    if (i == 0) row_ptr[NN] = NE;
}

// ---------------- CSR fill: csr[pos] = {src, norm} ----------------
__global__ __launch_bounds__(256) void k_fill(const int* __restrict__ src,
                                              const int* __restrict__ dst,
                                              const float* __restrict__ dinv,
                                              int* __restrict__ fill,
                                              int2* __restrict__ csr) {
    int e = blockIdx.x * 256 + threadIdx.x;
    if (e >= NE) return;
    int s = src[e], d = dst[e];
    float nrm = dinv[s] * dinv[d];
    int pos = atomicAdd(&fill[d], 1);
    csr[pos] = make_int2(s, __float_as_int(nrm));
}

// ---------------- gather: agg[v] = h[v]*dinv[v]^2 + sum_in h[s]*norm ----------------
__global__ __launch_bounds__(256) void k_gather(const _Float16* __restrict__ hh,
                                                const int* __restrict__ row_ptr,
                                                const int2* __restrict__ csr,
                                                const float* __restrict__ dinv,
                                                _Float16* __restrict__ agg) {
    int t = blockIdx.x * 256 + threadIdx.x;   // NN*32 threads
    int v = t >> 5;
    if (v >= NN) return;
    int c = (t & 31) * 4;

    float di = dinv[v];
    float sl = di * di;
    h4 hv = *(const h4*)(hh + (size_t)v * D + c);
    float4 acc = make_float4((float)hv.x * sl, (float)hv.y * sl,
                             (float)hv.z * sl, (float)hv.w * sl);

    int p   = row_ptr[v];
    int end = row_ptr[v + 1];
    for (; p + 3 < end; p += 4) {
        int2 e0 = csr[p], e1 = csr[p + 1], e2 = csr[p + 2], e3 = csr[p + 3];
        float n0 = __int_as_float(e0.y);
        float n1 = __int_as_float(e1.y);
        float n2 = __int_as_float(e2.y);
        float n3 = __int_as_float(e3.y);
        h4 g0 = *(const h4*)(hh + (size_t)e0.x * D + c);
        h4 g1 = *(const h4*)(hh + (size_t)e1.x * D + c);
        h4 g2 = *(const h4*)(hh + (size_t)e2.x * D + c);
        h4 g3 = *(const h4*)(hh + (size_t)e3.x * D + c);
        acc.x += (float)g0.x * n0; acc.y += (float)g0.y * n0;
        acc.z += (float)g0.z * n0; acc.w += (float)g0.w * n0;
        acc.x += (float)g1.x * n1; acc.y += (float)g1.y * n1;
        acc.z += (float)g1.z * n1; acc.w += (float)g1.w * n1;
        acc.x += (float)g2.x * n2; acc.y += (float)g2.y * n2;
        acc.z += (float)g2.z * n2; acc.w += (float)g2.w * n2;
        acc.x += (float)g3.x * n3; acc.y += (float)g3.y * n3;
        acc.z += (float)g3.z * n3; acc.w += (float)g3.w * n3;
    }
    for (; p < end; ++p) {
        int2 e0 = csr[p];
        float n0 = __int_as_float(e0.y);
        h4 g0 = *(const h4*)(hh + (size_t)e0.x * D + c);
        acc.x += (float)g0.x * n0; acc.y += (float)g0.y * n0;
        acc.z += (float)g0.z * n0; acc.w += (float)g0.w * n0;
    }
    h4 ov = {(_Float16)acc.x, (_Float16)acc.y, (_Float16)acc.z, (_Float16)acc.w};
    *(h4*)(agg + (size_t)v * D + c) = ov;
}

// ---------------- fused pool + classifier (block per graph) ----------------
__global__ __launch_bounds__(128) void k_poolcls(const _Float16* __restrict__ agg,
                                                 const float* __restrict__ b2,
                                                 const int* __restrict__ gstart,
                                                 const float* __restrict__ Wc,
                                                 const float* __restrict__ bc,
                                                 float* __restrict__ out) {
    int g = blockIdx.x;
    int c = threadIdx.x;
    int v0 = gstart[g], v1 = gstart[g + 1];
    float bb = b2[c];
    float acc = 0.f;
    int v = v0;
    for (; v + 7 < v1; v += 8) {            // 8-deep for latency
        float x0 = (float)agg[(size_t)(v + 0) * D + c];
        float x1 = (float)agg[(size_t)(v + 1) * D + c];
        float x2 = (float)agg[(size_t)(v + 2) * D + c];
        float x3 = (float)agg[(size_t)(v + 3) * D + c];
        float x4 = (float)agg[(size_t)(v + 4) * D + c];
        float x5 = (float)agg[(size_t)(v + 5) * D + c];
        float x6 = (float)agg[(size_t)(v + 6) * D + c];
        float x7 = (float)agg[(size_t)(v + 7) * D + c];
        acc += fmaxf(x0 + bb, 0.f) + fmaxf(x1 + bb, 0.f)
             + fmaxf(x2 + bb, 0.f) + fmaxf(x3 + bb, 0.f)
             + fmaxf(x4 + bb, 0.f) + fmaxf(x5 + bb, 0.f)
             + fmaxf(x6 + bb, 0.f) + fmaxf(x7 + bb, 0.f);
    }
    for (; v < v1; ++v)
        acc += fmaxf((float)agg[(size_t)v * D + c] + bb, 0.f);

    float inv = 1.0f / fmaxf((float)(v1 - v0), 1.0f);
    float pv = acc * inv;

    __shared__ float red[2][128];
    red[0][c] = pv * Wc[c * 2 + 0];
    red[1][c] = pv * Wc[c * 2 + 1];
    __syncthreads();
    if (c < 64) {
        float s = red[0][c] + red[0][c + 64];
        for (int off = 32; off; off >>= 1) s += __shfl_down(s, off);
        if (c == 0) out[g * 2 + 0] = s + bc[0];
    } else {
        int l = c - 64;
        float s = red[1][l] + red[1][l + 64];
        for (int off = 32; off; off >>= 1) s += __shfl_down(s, off);
        if (l == 0) out[g * 2 + 1] = s + bc[1];
    }
}

extern "C" void kernel_launch(void* const* d_in, const int* in_sizes, int n_in,
                              void* d_out, int out_size, void* d_ws, size_t ws_size,
                              hipStream_t stream) {
    const float* x     = (const float*)d_in[0];
    const int*   ei    = (const int*)d_in[1];
    const int*   batch = (const int*)d_in[2];
    const float* W1    = (const float*)d_in[3];
    const float* b1    = (const float*)d_in[4];
    const float* W2    = (const float*)d_in[5];
    const float* b2    = (const float*)d_in[6];
    const float* Wc    = (const float*)d_in[7];
    const float* bc    = (const float*)d_in[8];
    float* out = (float*)d_out;

    const int* src = ei;            // edge_index[0]
    const int* dst = ei + NE;       // edge_index[1]

    char* p = (char*)d_ws;
    int*       deg_i   = (int*)p;       p += 100352 * 4;
    float*     dinv    = (float*)p;     p += 100352 * 4;
    int*       row_ptr = (int*)p;       p += 100352 * 4;   // NN+1 fits
    int*       fillc   = (int*)p;       p += 100352 * 4;
    int*       bsum    = (int*)p;       p += 256 * 4;
    int*       gstart  = (int*)p;       p += 1056 * 4;     // NG+1
    _Float16*  Wt1     = (_Float16*)p;  p += 16384 * 2;
    _Float16*  Wt2     = (_Float16*)p;  p += 16384 * 2;
    int2*      csr     = (int2*)p;      p += (size_t)NE * 8;
    _Float16*  bufA    = (_Float16*)p;  p += (size_t)NN * D * 2;
    _Float16*  bufB    = (_Float16*)p;  p += (size_t)NN * D * 2;

    hipMemsetAsync(deg_i, 0, 100352 * 4, stream);

    // K1: degree histogram || W1/W2 transpose+fp16
    k_pre<<<HIST_BLKS + 2, 256, 0, stream>>>(dst, deg_i, W1, W2, Wt1, Wt2);
    // K2: scan phase A (+dinv) || graph bounds
    k_scanA<<<NB + BOUNDS_BLKS, 256, 0, stream>>>(deg_i, dinv, row_ptr, bsum, batch, gstart);
    // K3: scan finalize
    k_scanC<<<(NN + 255) / 256, 256, 0, stream>>>(row_ptr, bsum, fillc);
    // K4: CSR fill
    k_fill<<<HIST_BLKS, 256, 0, stream>>>(src, dst, dinv, fillc, csr);

    // layer 1: MFMA GEMM (x fp32 -> fp16 h1), gather
    k_gemm1<<<GEMM_BLKS, 256, 0, stream>>>(x, Wt1, bufA);
    k_gather<<<NN * 32 / 256, 256, 0, stream>>>(bufA, row_ptr, csr, dinv, bufB);

    // layer 2: MFMA GEMM (relu(agg1+b1) fp16 -> h2), gather
    k_gemm2<<<GEMM_BLKS, 256, 0, stream>>>(bufB, Wt2, b1, bufA);
    k_gather<<<NN * 32 / 256, 256, 0, stream>>>(bufA, row_ptr, csr, dinv, bufB);

    // fused pooling (bias2+relu) + classifier
    k_poolcls<<<NG, 128, 0, stream>>>(bufB, b2, gstart, Wc, bc, out);
}